// Round 11
// baseline (1442.314 us; speedup 1.0000x reference)
//
#include <hip/hip_runtime.h>

#define HH 32
#define LOG2E 1.44269504088896340736f

typedef float v2f __attribute__((ext_vector_type(2)));

// DPP quad_perm controls: xor within the 4-lane gate group (q = lane&3)
#define QP_XOR1 0xB1   // [1,0,3,2]
#define QP_XOR2 0x4E   // [2,3,0,1]
#define QP_XOR3 0x1B   // [3,2,1,0]
#define QPERM(v, ctrl) \
    __int_as_float(__builtin_amdgcn_update_dpp(0, __float_as_int(v), (ctrl), 0xF, 0xF, true))

__device__ __forceinline__ float hw_exp2(float x) {
    float r; asm("v_exp_f32 %0, %1" : "=v"(r) : "v"(x)); return r;
}
__device__ __forceinline__ float sigm_e(float z, float e) {
    // 1/(1+exp2(z*e)); sigmoid(z) when e = -log2(e)
    return __builtin_amdgcn_rcpf(1.0f + hw_exp2(z * e));
}
__device__ __forceinline__ v2f pk_fma(v2f a, v2f b, v2f c) {
    return __builtin_elementwise_fma(a, b, c);   // v_pk_fma_f32, ACC operands fold
}
__device__ __forceinline__ void load_bc(const float* p, v2f* d) {
#pragma unroll
    for (int r = 0; r < 8; ++r) {                // 8x ds_read_b128 broadcast
        float4 v = ((const float4*)p)[r];
        d[2*r]   = (v2f){v.x, v.y};
        d[2*r+1] = (v2f){v.z, v.w};
    }
}

// One 64-lane wave per batch element; 4 independent waves per block; NO barriers.
// lane: q = lane&3 (gate 0=i 1=f 2=g 3=o), c = lane>>2 (0..15).
// Lane owns gate rows rowA=(q<<5)|c (channel c) and rowB=(q<<5)|(c+16) (channel c+16).
__global__ __launch_bounds__(256, 1)
void lstm_seq_kernel(const float* __restrict__ input,
                     const float* __restrict__ W_ih1, const float* __restrict__ W_hh1,
                     const float* __restrict__ b_ih1, const float* __restrict__ b_hh1,
                     const float* __restrict__ W_ih2, const float* __restrict__ W_hh2,
                     const float* __restrict__ b_ih2, const float* __restrict__ b_hh2,
                     const float* __restrict__ W_lin, const float* __restrict__ b_lin,
                     float* __restrict__ out, int T, int total)
{
    const int tid  = threadIdx.x;
    const int w    = tid >> 6;                 // wave index in block (element)
    const int lane = tid & 63;
    const int e    = blockIdx.x * 4 + w;       // batch element
    const int q    = lane & 3;
    const int c    = lane >> 2;                // channel 0..15 (A); c+16 (B)
    const int rowA = (q << 5) | c;
    const int rowB = (q << 5) | (c + 16);

    __shared__ __align__(16) float lds[4][64]; // per-wave: [0..31]=h1, [32..63]=h2
    float* h1buf = &lds[w][0];
    float* h2buf = &lds[w][32];

    // ---- resident weights: 2 rows x 3 matrices x 32 + W_lin = 224 regs/lane ----
    v2f wh1A[16], wh1B[16], wi2A[16], wi2B[16], wh2A[16], wh2B[16], wlv[16];
    {
        const v2f* a1 = (const v2f*)(W_hh1 + rowA * HH);
        const v2f* b1p = (const v2f*)(W_hh1 + rowB * HH);
        const v2f* a2 = (const v2f*)(W_ih2 + rowA * HH);
        const v2f* b2p = (const v2f*)(W_ih2 + rowB * HH);
        const v2f* a3 = (const v2f*)(W_hh2 + rowA * HH);
        const v2f* b3p = (const v2f*)(W_hh2 + rowB * HH);
        const v2f* pl = (const v2f*)(W_lin);
#pragma unroll
        for (int r = 0; r < 16; ++r) {
            wh1A[r] = a1[r]; wh1B[r] = b1p[r];
            wi2A[r] = a2[r]; wi2B[r] = b2p[r];
            wh2A[r] = a3[r]; wh2B[r] = b3p[r];
            wlv[r]  = pl[r];
        }
    }
    const float wxA = W_ih1[rowA], wxB = W_ih1[rowB];
    const float b1A = b_ih1[rowA] + b_hh1[rowA];
    const float b1B = b_ih1[rowB] + b_hh1[rowB];
    const float b2A = b_ih2[rowA] + b_hh2[rowA];
    const float b2B = b_ih2[rowB] + b_hh2[rowB];
    const float blin = b_lin[0];

    // gate g (q==2) uses tanh = 2*sigmoid(2z)-1; i/f/o use sigmoid
    const bool  isg = (q == 2);
    const float es  = isg ? (-2.0f * LOG2E) : (-LOG2E);
    const float mm  = isg ? 2.0f : 1.0f;
    const float cc  = isg ? -1.0f : 0.0f;

    float c1A = 0.f, c1B = 0.f, c2A = 0.f, c2B = 0.f;  // valid on q==0 lanes
    float ov = 0.0f;
    // carried z1 partials (include bias): a = b1 + Whh1·h1(t-1)
    v2f aA0 = {b1A, 0.f}, aA1 = {0.f, 0.f};
    v2f aB0 = {b1B, 0.f}, aB1 = {0.f, 0.f};
    // carried z2 partials (include bias): ec = b2 + Whh2·h2(t-1)
    v2f eA0 = {b2A, 0.f}, eA1 = {0.f, 0.f};
    v2f eB0 = {b2B, 0.f}, eB1 = {0.f, 0.f};

    const float* __restrict__ inp  = input + (size_t)e * T;
    float* __restrict__       outp = out   + (size_t)e * total;
    float xcur = inp[0];

    for (int t = 0; t < total; ++t) {
        float x = (t < T) ? xcur : ov;
        int tn = t + 1;
        xcur = inp[tn < T ? tn : (T - 1)];               // prefetch, off-path

        // ---------- cell 1 (both channel halves) ----------
        float z1A = fmaf(x, wxA, (aA0.x + aA0.y) + (aA1.x + aA1.y));
        float z1B = fmaf(x, wxB, (aB0.x + aB0.y) + (aB1.x + aB1.y));
        float acA = fmaf(mm, sigm_e(z1A, es), cc);       // sig(i/f/o) | tanh(g)
        float acB = fmaf(mm, sigm_e(z1B, es), cc);
        float fA = QPERM(acA, QP_XOR1), gA = QPERM(acA, QP_XOR2), oA = QPERM(acA, QP_XOR3);
        float fB = QPERM(acB, QP_XOR1), gB = QPERM(acB, QP_XOR2), oB = QPERM(acB, QP_XOR3);
        c1A = fmaf(fA, c1A, acA * gA);
        c1B = fmaf(fB, c1B, acB * gB);
        float h1A = oA * fmaf(2.0f, sigm_e(c1A, -2.0f * LOG2E), -1.0f);
        float h1B = oB * fmaf(2.0f, sigm_e(c1B, -2.0f * LOG2E), -1.0f);
        if (q == 0) { h1buf[c] = h1A; h1buf[c + 16] = h1B; }

        v2f h1v[16]; load_bc(h1buf, h1v);                // same-wave round-trip

        // ---------- cell 2: z2 = ec + Wi2·h1 ----------
        v2f sA0 = eA0, sA1 = eA1, sB0 = eB0, sB1 = eB1;
#pragma unroll
        for (int r = 0; r < 16; r += 2) {
            sA0 = pk_fma(h1v[r],   wi2A[r],   sA0);
            sA1 = pk_fma(h1v[r+1], wi2A[r+1], sA1);
            sB0 = pk_fma(h1v[r],   wi2B[r],   sB0);
            sB1 = pk_fma(h1v[r+1], wi2B[r+1], sB1);
        }
        float z2A = (sA0.x + sA0.y) + (sA1.x + sA1.y);
        float z2B = (sB0.x + sB0.y) + (sB1.x + sB1.y);
        float dcA = fmaf(mm, sigm_e(z2A, es), cc);
        float dcB = fmaf(mm, sigm_e(z2B, es), cc);
        float fA2 = QPERM(dcA, QP_XOR1), gA2 = QPERM(dcA, QP_XOR2), oA2 = QPERM(dcA, QP_XOR3);
        float fB2 = QPERM(dcB, QP_XOR1), gB2 = QPERM(dcB, QP_XOR2), oB2 = QPERM(dcB, QP_XOR3);
        c2A = fmaf(fA2, c2A, dcA * gA2);
        c2B = fmaf(fB2, c2B, dcB * gB2);
        float h2A = oA2 * fmaf(2.0f, sigm_e(c2A, -2.0f * LOG2E), -1.0f);
        float h2B = oB2 * fmaf(2.0f, sigm_e(c2B, -2.0f * LOG2E), -1.0f);
        if (q == 0) { h2buf[c] = h2A; h2buf[c + 16] = h2B; }

        // next-step z1 carry (uses h1v, independent of h2) fills the read shadow
        aA0 = (v2f){b1A, 0.f}; aA1 = (v2f){0.f, 0.f};
        aB0 = (v2f){b1B, 0.f}; aB1 = (v2f){0.f, 0.f};
#pragma unroll
        for (int r = 0; r < 16; r += 2) {
            aA0 = pk_fma(h1v[r],   wh1A[r],   aA0);
            aA1 = pk_fma(h1v[r+1], wh1A[r+1], aA1);
            aB0 = pk_fma(h1v[r],   wh1B[r],   aB0);
            aB1 = pk_fma(h1v[r+1], wh1B[r+1], aB1);
        }

        v2f h2v[16]; load_bc(h2buf, h2v);                // same-wave round-trip

        // output dot (redundant per-lane) — critical for AR feedback
        v2f o0 = {blin, 0.f}, o1 = {0.f, 0.f};
#pragma unroll
        for (int r = 0; r < 16; r += 2) {
            o0 = pk_fma(h2v[r],   wlv[r],   o0);
            o1 = pk_fma(h2v[r+1], wlv[r+1], o1);
        }
        ov = (o0.x + o0.y) + (o1.x + o1.y);
        if (lane == 0) outp[t] = ov;

        // next-step z2 carry (uses h2v, off the feedback path)
        eA0 = (v2f){b2A, 0.f}; eA1 = (v2f){0.f, 0.f};
        eB0 = (v2f){b2B, 0.f}; eB1 = (v2f){0.f, 0.f};
#pragma unroll
        for (int r = 0; r < 16; r += 2) {
            eA0 = pk_fma(h2v[r],   wh2A[r],   eA0);
            eA1 = pk_fma(h2v[r+1], wh2A[r+1], eA1);
            eB0 = pk_fma(h2v[r],   wh2B[r],   eB0);
            eB1 = pk_fma(h2v[r+1], wh2B[r+1], eB1);
        }
    }
}

extern "C" void kernel_launch(void* const* d_in, const int* in_sizes, int n_in,
                              void* d_out, int out_size, void* d_ws, size_t ws_size,
                              hipStream_t stream) {
    const int B = 1024;                 // fixed by the source module
    const int T = in_sizes[0] / B;      // 999
    const int total = out_size / B;     // T + future = 1999

    lstm_seq_kernel<<<dim3(B / 4), dim3(256), 0, stream>>>(
        (const float*)d_in[0],
        (const float*)d_in[1], (const float*)d_in[2],
        (const float*)d_in[3], (const float*)d_in[4],
        (const float*)d_in[5], (const float*)d_in[6],
        (const float*)d_in[7], (const float*)d_in[8],
        (const float*)d_in[9], (const float*)d_in[10],
        (float*)d_out, T, total);
}

// Round 12
// 1209.157 us; speedup vs baseline: 1.1928x; 1.1928x over previous
//
#include <hip/hip_runtime.h>

#define HH 32
#define LOG2E 1.44269504088896340736f
#define KCH 16   // TF pipeline chunk length (steps per ring half)

typedef float v2f __attribute__((ext_vector_type(2)));

// DPP: quad_perm broadcasts (gate q = lane&3) and row rotates (16-lane rows)
#define DPPF(v, ctrl) \
    __int_as_float(__builtin_amdgcn_update_dpp(0, __float_as_int(v), (ctrl), 0xF, 0xF, true))
#define QP_B0 0x00   // [0,0,0,0] -> gate i to all quad lanes
#define QP_B1 0x55   // [1,1,1,1] -> gate f
#define QP_B2 0xAA   // [2,2,2,2] -> gate g
#define QP_B3 0xFF   // [3,3,3,3] -> gate o
#define DPP_ROR4  0x124
#define DPP_ROR8  0x128
#define SWZ(v, pat) __int_as_float(__builtin_amdgcn_ds_swizzle(__float_as_int(v), (pat)))

__device__ __forceinline__ float hw_exp2(float x) {
    float r; asm("v_exp_f32 %0, %1" : "=v"(r) : "v"(x)); return r;
}
__device__ __forceinline__ float sigm_e(float z, float e) {
    return __builtin_amdgcn_rcpf(1.0f + hw_exp2(z * e));
}
__device__ __forceinline__ v2f pk_fma(v2f a, v2f b, v2f c) {
    return __builtin_elementwise_fma(a, b, c);   // v_pk_fma_f32
}
__device__ __forceinline__ void load_bc(const float* p, v2f* d) {
#pragma unroll
    for (int r = 0; r < 8; ++r) {                // 8x ds_read_b128 broadcast
        float4 v = ((const float4*)p)[r];
        d[2*r]   = (v2f){v.x, v.y};
        d[2*r+1] = (v2f){v.z, v.w};
    }
}
// sum over 16 channels-groups: lanes hold p per (q,ch); rows of 16 lanes hold 4 ch
__device__ __forceinline__ float out_reduce(float p) {
    p += DPPF(p, DPP_ROR4);          // + ch rotated by 1 within row
    p += DPPF(p, DPP_ROR8);          // now each lane = sum of its row's 4 ch
    p += SWZ(p, 0x401F);             // xor16: combine row pairs within 32-group
    p += __shfl_xor(p, 32, 64);      // combine halves -> all 64 lanes = total
    return p;
}

// Layout (both waves): q=lane&3 (gate 0=i 1=f 2=g 3=o), ch=lane>>2 (0..15).
// Lane owns rows rowA=(q<<5)|ch and rowB=(q<<5)|(ch+16).
// Gate combine = 4 quad_perm broadcasts -> every lane computes c,h redundantly.
__global__ __launch_bounds__(128, 2)
void lstm_seq_kernel(const float* __restrict__ input,
                     const float* __restrict__ W_ih1, const float* __restrict__ W_hh1,
                     const float* __restrict__ b_ih1, const float* __restrict__ b_hh1,
                     const float* __restrict__ W_ih2, const float* __restrict__ W_hh2,
                     const float* __restrict__ b_ih2, const float* __restrict__ b_hh2,
                     const float* __restrict__ W_lin, const float* __restrict__ b_lin,
                     float* __restrict__ out, int T, int total)
{
    const int b    = blockIdx.x;     // one block (2 waves) per batch element
    const int tid  = threadIdx.x;
    const int w    = tid >> 6;       // wave0 = cell1, wave1 = cell2 + output
    const int lane = tid & 63;
    const int q    = lane & 3;
    const int ch   = lane >> 2;      // 0..15
    const int rowA = (q << 5) | ch;
    const int rowB = (q << 5) | (ch + 16);

    __shared__ __align__(16) float ring[2 * KCH * HH];  // h1 stream (TF)
    __shared__ __align__(16) float h1x[HH];             // AR h1 exchange
    __shared__ __align__(16) float h2s[HH];             // wave1 h2 self-broadcast
    __shared__ float xbuf;                              // AR feedback

    const bool  isg = (q == 2);
    const float es  = isg ? (-2.0f * LOG2E) : (-LOG2E);
    const float mm  = isg ? 2.0f : 1.0f;
    const float cc  = isg ? -1.0f : 0.0f;

    // ---- per-wave weights ----
    v2f m1A[16], m1B[16], m2A[16], m2B[16];   // wave0: m1=Whh1. wave1: m1=Wih2, m2=Whh2
    float wxA = 0.f, wxB = 0.f, bA, bB, wlA = 0.f, wlB = 0.f, blin = 0.f;
    if (w == 0) {
        const v2f* pA = (const v2f*)(W_hh1 + rowA * HH);
        const v2f* pB = (const v2f*)(W_hh1 + rowB * HH);
#pragma unroll
        for (int r = 0; r < 16; ++r) { m1A[r] = pA[r]; m1B[r] = pB[r]; }
        wxA = W_ih1[rowA]; wxB = W_ih1[rowB];
        bA  = b_ih1[rowA] + b_hh1[rowA];
        bB  = b_ih1[rowB] + b_hh1[rowB];
    } else {
        const v2f* pA = (const v2f*)(W_ih2 + rowA * HH);
        const v2f* pB = (const v2f*)(W_ih2 + rowB * HH);
        const v2f* qA = (const v2f*)(W_hh2 + rowA * HH);
        const v2f* qB = (const v2f*)(W_hh2 + rowB * HH);
#pragma unroll
        for (int r = 0; r < 16; ++r) { m1A[r] = pA[r]; m1B[r] = pB[r];
                                       m2A[r] = qA[r]; m2B[r] = qB[r]; }
        bA  = b_ih2[rowA] + b_hh2[rowA];
        bB  = b_ih2[rowB] + b_hh2[rowB];
        wlA = W_lin[ch]; wlB = W_lin[ch + 16]; blin = b_lin[0];
    }

    float cA = 0.f, cB = 0.f;        // c1 (wave0) / c2 (wave1), redundant on all lanes
    // carried pure dots: wave0: Whh1·h1(t-1); wave1: Whh2·h2(t-1)
    v2f p0 = {0.f,0.f}, p1 = {0.f,0.f}, p2 = {0.f,0.f}, p3 = {0.f,0.f};

    const float* __restrict__ inp  = input + (size_t)b * T;
    float* __restrict__       outp = out   + (size_t)b * total;

    // ================= Teacher-forced phase: chunk pipeline =================
    if (w == 0) {
        int t = 0;
        float xcur = inp[0];
        for (int cb = 0; t < T; ++cb) {
            float* buf = ring + (cb & 1) * (KCH * HH);
            int S = T - t; if (S > KCH) S = KCH;
            for (int s = 0; s < S; ++s, ++t) {
                float x = xcur;
                int tn = t + 1;
                xcur = inp[tn < T ? tn : 0];            // prefetch, off-path
                float z1A = fmaf(x, wxA, bA + (p0.x + p0.y) + (p1.x + p1.y));
                float z1B = fmaf(x, wxB, bB + (p2.x + p2.y) + (p3.x + p3.y));
                float acA = fmaf(mm, sigm_e(z1A, es), cc);
                float acB = fmaf(mm, sigm_e(z1B, es), cc);
                float iA = DPPF(acA, QP_B0), fA = DPPF(acA, QP_B1);
                float gA = DPPF(acA, QP_B2), oA = DPPF(acA, QP_B3);
                float iB = DPPF(acB, QP_B0), fB = DPPF(acB, QP_B1);
                float gB = DPPF(acB, QP_B2), oB = DPPF(acB, QP_B3);
                cA = fmaf(fA, cA, iA * gA);
                cB = fmaf(fB, cB, iB * gB);
                float hA = oA * fmaf(2.0f, sigm_e(cA, -2.0f * LOG2E), -1.0f);
                float hB = oB * fmaf(2.0f, sigm_e(cB, -2.0f * LOG2E), -1.0f);
                float* slot = buf + s * HH;
                if (q == 0) { slot[ch] = hA; slot[ch + 16] = hB; }
                v2f hv[16]; load_bc(slot, hv);           // same-wave round trip
                p0 = (v2f){0.f,0.f}; p1 = (v2f){0.f,0.f};
                p2 = (v2f){0.f,0.f}; p3 = (v2f){0.f,0.f};
#pragma unroll
                for (int r = 0; r < 16; r += 2) {
                    p0 = pk_fma(hv[r],   m1A[r],   p0);
                    p1 = pk_fma(hv[r+1], m1A[r+1], p1);
                    p2 = pk_fma(hv[r],   m1B[r],   p2);
                    p3 = pk_fma(hv[r+1], m1B[r+1], p3);
                }
            }
            __syncthreads();          // chunk published
        }
        __syncthreads();              // match consumer
    } else {
        __syncthreads();              // wait for chunk 0
        int t = 0;
        for (int cb = 0; t < T; ++cb) {
            const float* buf = ring + (cb & 1) * (KCH * HH);
            int S = T - t; if (S > KCH) S = KCH;
            for (int s = 0; s < S; ++s, ++t) {
                v2f hv[16]; load_bc(buf + s * HH, hv);
                v2f s0 = p0, s1 = p1, s2 = p2, s3 = p3;
#pragma unroll
                for (int r = 0; r < 16; r += 2) {
                    s0 = pk_fma(hv[r],   m1A[r],   s0);
                    s1 = pk_fma(hv[r+1], m1A[r+1], s1);
                    s2 = pk_fma(hv[r],   m1B[r],   s2);
                    s3 = pk_fma(hv[r+1], m1B[r+1], s3);
                }
                float z2A = bA + (s0.x + s0.y) + (s1.x + s1.y);
                float z2B = bB + (s2.x + s2.y) + (s3.x + s3.y);
                float acA = fmaf(mm, sigm_e(z2A, es), cc);
                float acB = fmaf(mm, sigm_e(z2B, es), cc);
                float iA = DPPF(acA, QP_B0), fA = DPPF(acA, QP_B1);
                float gA = DPPF(acA, QP_B2), oA = DPPF(acA, QP_B3);
                float iB = DPPF(acB, QP_B0), fB = DPPF(acB, QP_B1);
                float gB = DPPF(acB, QP_B2), oB = DPPF(acB, QP_B3);
                cA = fmaf(fA, cA, iA * gA);
                cB = fmaf(fB, cB, iB * gB);
                float hA = oA * fmaf(2.0f, sigm_e(cA, -2.0f * LOG2E), -1.0f);
                float hB = oB * fmaf(2.0f, sigm_e(cB, -2.0f * LOG2E), -1.0f);
                if (q == 0) { h2s[ch] = hA; h2s[ch + 16] = hB; }
                v2f gv[16]; load_bc(h2s, gv);            // same-wave round trip
                p0 = (v2f){0.f,0.f}; p1 = (v2f){0.f,0.f};
                p2 = (v2f){0.f,0.f}; p3 = (v2f){0.f,0.f};
#pragma unroll
                for (int r = 0; r < 16; r += 2) {
                    p0 = pk_fma(gv[r],   m2A[r],   p0);
                    p1 = pk_fma(gv[r+1], m2A[r+1], p1);
                    p2 = pk_fma(gv[r],   m2B[r],   p2);
                    p3 = pk_fma(gv[r+1], m2B[r+1], p3);
                }
                float pr = fmaf(hA, wlA, hB * wlB);
                float ov = out_reduce(pr) + blin;
                if (lane == 0) { outp[t] = ov; xbuf = ov; }
            }
            __syncthreads();
        }
    }

    // ================= Autoregressive phase: 2 barriers/step =================
    for (int t = T; t < total; ++t) {
        __syncthreads();                        // BX: xbuf (and h1x WAR) safe
        if (w == 0) {
            float x = xbuf;                     // LDS broadcast read
            float z1A = fmaf(x, wxA, bA + (p0.x + p0.y) + (p1.x + p1.y));
            float z1B = fmaf(x, wxB, bB + (p2.x + p2.y) + (p3.x + p3.y));
            float acA = fmaf(mm, sigm_e(z1A, es), cc);
            float acB = fmaf(mm, sigm_e(z1B, es), cc);
            float iA = DPPF(acA, QP_B0), fA = DPPF(acA, QP_B1);
            float gA = DPPF(acA, QP_B2), oA = DPPF(acA, QP_B3);
            float iB = DPPF(acB, QP_B0), fB = DPPF(acB, QP_B1);
            float gB = DPPF(acB, QP_B2), oB = DPPF(acB, QP_B3);
            cA = fmaf(fA, cA, iA * gA);
            cB = fmaf(fB, cB, iB * gB);
            float hA = oA * fmaf(2.0f, sigm_e(cA, -2.0f * LOG2E), -1.0f);
            float hB = oB * fmaf(2.0f, sigm_e(cB, -2.0f * LOG2E), -1.0f);
            if (q == 0) { h1x[ch] = hA; h1x[ch + 16] = hB; }
        } else {
            v2f gv[16]; load_bc(h2s, gv);       // own write from prev step
            p0 = (v2f){0.f,0.f}; p1 = (v2f){0.f,0.f};
            p2 = (v2f){0.f,0.f}; p3 = (v2f){0.f,0.f};
#pragma unroll
            for (int r = 0; r < 16; r += 2) {
                p0 = pk_fma(gv[r],   m2A[r],   p0);
                p1 = pk_fma(gv[r+1], m2A[r+1], p1);
                p2 = pk_fma(gv[r],   m2B[r],   p2);
                p3 = pk_fma(gv[r+1], m2B[r+1], p3);
            }
        }
        __syncthreads();                        // BH: h1x visible
        if (w == 0) {
            v2f hv[16]; load_bc(h1x, hv);       // next z1 carry (shadow)
            p0 = (v2f){0.f,0.f}; p1 = (v2f){0.f,0.f};
            p2 = (v2f){0.f,0.f}; p3 = (v2f){0.f,0.f};
#pragma unroll
            for (int r = 0; r < 16; r += 2) {
                p0 = pk_fma(hv[r],   m1A[r],   p0);
                p1 = pk_fma(hv[r+1], m1A[r+1], p1);
                p2 = pk_fma(hv[r],   m1B[r],   p2);
                p3 = pk_fma(hv[r+1], m1B[r+1], p3);
            }
        } else {
            v2f hv[16]; load_bc(h1x, hv);
            v2f s0 = p0, s1 = p1, s2 = p2, s3 = p3;
#pragma unroll
            for (int r = 0; r < 16; r += 2) {
                s0 = pk_fma(hv[r],   m1A[r],   s0);
                s1 = pk_fma(hv[r+1], m1A[r+1], s1);
                s2 = pk_fma(hv[r],   m1B[r],   s2);
                s3 = pk_fma(hv[r+1], m1B[r+1], s3);
            }
            float z2A = bA + (s0.x + s0.y) + (s1.x + s1.y);
            float z2B = bB + (s2.x + s2.y) + (s3.x + s3.y);
            float acA = fmaf(mm, sigm_e(z2A, es), cc);
            float acB = fmaf(mm, sigm_e(z2B, es), cc);
            float iA = DPPF(acA, QP_B0), fA = DPPF(acA, QP_B1);
            float gA = DPPF(acA, QP_B2), oA = DPPF(acA, QP_B3);
            float iB = DPPF(acB, QP_B0), fB = DPPF(acB, QP_B1);
            float gB = DPPF(acB, QP_B2), oB = DPPF(acB, QP_B3);
            cA = fmaf(fA, cA, iA * gA);
            cB = fmaf(fB, cB, iB * gB);
            float hA = oA * fmaf(2.0f, sigm_e(cA, -2.0f * LOG2E), -1.0f);
            float hB = oB * fmaf(2.0f, sigm_e(cB, -2.0f * LOG2E), -1.0f);
            if (q == 0) { h2s[ch] = hA; h2s[ch + 16] = hB; }
            float pr = fmaf(hA, wlA, hB * wlB);
            float ov = out_reduce(pr) + blin;
            if (lane == 0) { outp[t] = ov; xbuf = ov; }
        }
    }
}

extern "C" void kernel_launch(void* const* d_in, const int* in_sizes, int n_in,
                              void* d_out, int out_size, void* d_ws, size_t ws_size,
                              hipStream_t stream) {
    const int B = 1024;                 // fixed by the source module
    const int T = in_sizes[0] / B;      // 999
    const int total = out_size / B;     // T + future = 1999

    lstm_seq_kernel<<<dim3(B), dim3(128), 0, stream>>>(
        (const float*)d_in[0],
        (const float*)d_in[1], (const float*)d_in[2],
        (const float*)d_in[3], (const float*)d_in[4],
        (const float*)d_in[5], (const float*)d_in[6],
        (const float*)d_in[7], (const float*)d_in[8],
        (const float*)d_in[9], (const float*)d_in[10],
        (float*)d_out, T, total);
}